// Round 1
// baseline (2010.359 us; speedup 1.0000x reference)
//
#include <hip/hip_runtime.h>
#include <math.h>

// 3-layer LSTM (H=64, D=300, B=256, T=512) + MLP head (64 -> tanh 64 -> 300).
// Runtime dtype dispatch (bf16 vs fp32) decided on-device; internal compute fp32.
// R4: all three GEMM kernels (proj0/projh/head) get bf16 MFMA paths (md==0).
//   - proj0: A already bf16 in memory -> direct MFMA (exact vs old path).
//   - projh/head: fp32 A operands split into hi+lo bf16 (2 MFMAs) => ~17
//     mantissa bits, fp32-grade accuracy preserved for the recurrence.
//   - fp32 VALU fallback (md==1) kept for correctness in fp32 mode.
// scan_chunk unchanged this round.

#define TT 512
#define BB 256
#define DD 300
#define HH 64
#define MM (TT * BB)
#define XP 256            // 4H
#define TC 128            // time chunk
#define NC (TT / TC)

typedef __attribute__((ext_vector_type(8))) short bf16x8;
typedef __attribute__((ext_vector_type(4))) float f32x4;

__device__ __forceinline__ float bf2f(unsigned short u) {
    return __uint_as_float(((unsigned int)u) << 16);
}
__device__ __forceinline__ unsigned short f2bf(float f) {
    unsigned int x = __float_as_uint(f);
    x += 0x7FFFu + ((x >> 16) & 1u);   // RNE
    return (unsigned short)(x >> 16);
}
__device__ __forceinline__ float sigm(float x) { return 1.f / (1.f + __expf(-x)); }
__device__ __forceinline__ float tanh_f(float x) { return 1.f - 2.f / (__expf(2.f * x) + 1.f); }

// dual-mode loads: md==1 -> fp32 buffer, md==0 -> bf16 buffer
__device__ __forceinline__ float ld1(const void* p, long long i, int md) {
    return md ? ((const float*)p)[i] : bf2f(((const unsigned short*)p)[i]);
}
__device__ __forceinline__ void ld4v(float* d, const void* p, long long i, int md) {
    if (md) {
        float4 v = *(const float4*)((const float*)p + i);
        d[0] = v.x; d[1] = v.y; d[2] = v.z; d[3] = v.w;
    } else {
        ushort4 u = *(const ushort4*)((const unsigned short*)p + i);
        d[0] = bf2f(u.x); d[1] = bf2f(u.y); d[2] = bf2f(u.z); d[3] = bf2f(u.w);
    }
}

__device__ __forceinline__ f32x4 mfma16(bf16x8 a, bf16x8 b, f32x4 c) {
    return __builtin_amdgcn_mfma_f32_16x16x32_bf16(a, b, c, 0, 0, 0);
}

#define FMA4x4(a, bv)                                        \
    acc[0][0] = fmaf((a).x, (bv).x, acc[0][0]);              \
    acc[0][1] = fmaf((a).x, (bv).y, acc[0][1]);              \
    acc[0][2] = fmaf((a).x, (bv).z, acc[0][2]);              \
    acc[0][3] = fmaf((a).x, (bv).w, acc[0][3]);              \
    acc[1][0] = fmaf((a).y, (bv).x, acc[1][0]);              \
    acc[1][1] = fmaf((a).y, (bv).y, acc[1][1]);              \
    acc[1][2] = fmaf((a).y, (bv).z, acc[1][2]);              \
    acc[1][3] = fmaf((a).y, (bv).w, acc[1][3]);              \
    acc[2][0] = fmaf((a).z, (bv).x, acc[2][0]);              \
    acc[2][1] = fmaf((a).z, (bv).y, acc[2][1]);              \
    acc[2][2] = fmaf((a).z, (bv).z, acc[2][2]);              \
    acc[2][3] = fmaf((a).z, (bv).w, acc[2][3]);              \
    acc[3][0] = fmaf((a).w, (bv).x, acc[3][0]);              \
    acc[3][1] = fmaf((a).w, (bv).y, acc[3][1]);              \
    acc[3][2] = fmaf((a).w, (bv).z, acc[3][2]);              \
    acc[3][3] = fmaf((a).w, (bv).w, acc[3][3]);

// ---------------------------------------------------------------------------
__global__ void detect_kernel(const void* inp, int* mode) {
    if (threadIdx.x == 0 && blockIdx.x == 0) {
        const unsigned short* u = (const unsigned short*)inp;
        int bad = 0;
        for (int i = 0; i < 256; ++i) {
            float f = bf2f(u[i]);
            if (!(f == f) || fabsf(f) > 1e6f) ++bad;
        }
        *mode = (bad >= 4) ? 1 : 0;
    }
}

__global__ __launch_bounds__(256) void init_state(
    const void* h0, const void* c0, float* hstate, float* cstate, const int* modep)
{
    const int md = *modep;
    int i = blockIdx.x * 256 + threadIdx.x;
    if (i < 3 * BB * HH) {
        hstate[i] = ld1(h0, i, md);
        cstate[i] = ld1(c0, i, md);
    }
}

__global__ __launch_bounds__(256) void final_state(
    const float* hstate, const float* cstate, void* out, const int* modep)
{
    const int md = *modep;
    int i = blockIdx.x * 256 + threadIdx.x;
    const long long base = (long long)MM * DD;
    if (i < 3 * BB * HH) {
        if (md) {
            ((float*)out)[base + i] = hstate[i];
            ((float*)out)[base + 3 * BB * HH + i] = cstate[i];
        } else {
            ((unsigned short*)out)[base + i] = f2bf(hstate[i]);
            ((unsigned short*)out)[base + 3 * BB * HH + i] = f2bf(cstate[i]);
        }
    }
}

// ---------------------------------------------------------------------------
// proj0_chunk: xp[ml][n] = sum_k input(b,t,k)*wih0[n][k] + bih0[n]+bhh0[n]
// ml = t_local*256+b, t = chunk*TC + t_local. grid (512,1), blk 256.
// md==0: MFMA bf16, tile M=64 x N=256 (full N -> A fetched once), K pad 320.
// ---------------------------------------------------------------------------
__global__ __launch_bounds__(256) void proj0_chunk(
    const void* __restrict__ inp, const void* __restrict__ wih,
    const void* __restrict__ bih, const void* __restrict__ bhh,
    float* __restrict__ xp, const int* modep, int chunk)
{
    const int md = *modep;
    __shared__ __align__(16) char smem[46080];   // max(mfma 46080, fp32 34816)
    const int tid = threadIdx.x;
    const int m0 = blockIdx.x * 64;
    if (md == 0) {
        // ---- MFMA bf16 path ----
        unsigned short* As = (unsigned short*)smem;            // [64][72]
        unsigned short* Ws = (unsigned short*)smem + 64 * 72;  // [256][72]
        const int lane = tid & 63;
        const int wv = tid >> 6;                 // wave -> n-quadrant
        const int fr = lane & 15, fq = lane >> 4;
        const int ar = tid >> 2;                 // staging row 0..63
        const int aq = (tid & 3) << 4;           // staging col base (elems)
        const int ml = m0 + ar;
        const int b = ml & 255;
        const int t = chunk * TC + (ml >> 8);
        const unsigned short* gA = (const unsigned short*)inp +
            (long long)b * (TT * DD) + (long long)t * DD;
        const unsigned short* gW = (const unsigned short*)wih + (long long)tid * DD;
        float bias[4];
        #pragma unroll
        for (int nf = 0; nf < 4; ++nf) {
            int n = wv * 64 + nf * 16 + fr;
            bias[nf] = ld1(bih, n, 0) + ld1(bhh, n, 0);
        }
        f32x4 acc[4][4] = {};
        for (int k0 = 0; k0 < 320; k0 += 64) {
            // stage A: row ar, 16 elems at aq (zero-pad k>=300)
            #pragma unroll
            for (int q = 0; q < 4; ++q) {
                int kg = k0 + aq + q * 4;
                ushort4 v = (kg < DD) ? *(const ushort4*)(gA + kg)
                                      : make_ushort4(0, 0, 0, 0);
                *(ushort4*)(As + ar * 72 + aq + q * 4) = v;
            }
            // stage W: row tid, 64 elems (zero-pad k>=300)
            #pragma unroll
            for (int q = 0; q < 16; ++q) {
                int kg = k0 + q * 4;
                ushort4 v = (kg < DD) ? *(const ushort4*)(gW + kg)
                                      : make_ushort4(0, 0, 0, 0);
                *(ushort4*)(Ws + tid * 72 + q * 4) = v;
            }
            __syncthreads();
            #pragma unroll
            for (int kf = 0; kf < 2; ++kf) {
                bf16x8 bfr[4], afr[4];
                #pragma unroll
                for (int nf = 0; nf < 4; ++nf)
                    bfr[nf] = *(const bf16x8*)(Ws + (wv * 64 + nf * 16 + fr) * 72 + kf * 32 + fq * 8);
                #pragma unroll
                for (int mf = 0; mf < 4; ++mf)
                    afr[mf] = *(const bf16x8*)(As + (mf * 16 + fr) * 72 + kf * 32 + fq * 8);
                #pragma unroll
                for (int mf = 0; mf < 4; ++mf) {
                    #pragma unroll
                    for (int nf = 0; nf < 4; ++nf)
                        acc[mf][nf] = mfma16(afr[mf], bfr[nf], acc[mf][nf]);
                }
            }
            __syncthreads();
        }
        // C/D layout: col = lane&15, row = (lane>>4)*4 + reg
        #pragma unroll
        for (int mf = 0; mf < 4; ++mf) {
            #pragma unroll
            for (int nf = 0; nf < 4; ++nf) {
                const int col = wv * 64 + nf * 16 + fr;
                #pragma unroll
                for (int r = 0; r < 4; ++r) {
                    const int row = m0 + mf * 16 + fq * 4 + r;
                    xp[(long long)row * XP + col] = acc[mf][nf][r] + bias[nf];
                }
            }
        }
    } else {
        // ---- fp32 VALU fallback (correctness mode) ----
        float (*At)[68] = (float (*)[68])smem;
        float (*Wt)[68] = (float (*)[68])(smem + 64 * 68 * 4);
        const int lr = tid >> 2;
        const int lc = (tid & 3) * 16;
        const int tx = tid & 15, ty = tid >> 4;
        const int ml = m0 + lr;
        const int b = ml & 255;
        const int t = chunk * TC + (ml >> 8);
        const long long abase = (long long)b * (TT * DD) + (long long)t * DD;
        for (int ny = 0; ny < 4; ++ny) {
            const int n0 = ny * 64;
            const long long wbase = (long long)(n0 + lr) * DD;
            float acc[4][4] = {{0.f,0.f,0.f,0.f},{0.f,0.f,0.f,0.f},{0.f,0.f,0.f,0.f},{0.f,0.f,0.f,0.f}};
            for (int k0 = 0; k0 < DD; k0 += 64) {
                if (k0 + lc + 15 < DD) {
                    #pragma unroll
                    for (int q = 0; q < 4; ++q) {
                        float va[4], vw[4];
                        ld4v(va, inp, abase + k0 + lc + q * 4, md);
                        ld4v(vw, wih, wbase + k0 + lc + q * 4, md);
                        #pragma unroll
                        for (int e = 0; e < 4; ++e) {
                            At[lc + q * 4 + e][lr] = va[e];
                            Wt[lc + q * 4 + e][lr] = vw[e];
                        }
                    }
                } else {
                    #pragma unroll
                    for (int q = 0; q < 16; ++q) {
                        int k = k0 + lc + q;
                        At[lc + q][lr] = (k < DD) ? ld1(inp, abase + k, md) : 0.f;
                        Wt[lc + q][lr] = (k < DD) ? ld1(wih, wbase + k, md) : 0.f;
                    }
                }
                __syncthreads();
                #pragma unroll 16
                for (int k = 0; k < 64; ++k) {
                    float4 a = *(const float4*)&At[k][ty * 4];
                    float4 bv = *(const float4*)&Wt[k][tx * 4];
                    FMA4x4(a, bv)
                }
                __syncthreads();
            }
            float bias[4];
            #pragma unroll
            for (int j = 0; j < 4; ++j) {
                int n = n0 + tx * 4 + j;
                bias[j] = ld1(bih, n, md) + ld1(bhh, n, md);
            }
            #pragma unroll
            for (int i = 0; i < 4; ++i) {
                long long row = m0 + ty * 4 + i;
                float4 o = make_float4(acc[i][0] + bias[0], acc[i][1] + bias[1],
                                       acc[i][2] + bias[2], acc[i][3] + bias[3]);
                *(float4*)(xp + row * XP + n0 + tx * 4) = o;
            }
        }
    }
}

// ---------------------------------------------------------------------------
// projh_chunk: xp[m][n] = sum_k A[m][k]*wih[n][k] + bih[n]+bhh[n]
// A fp32 [TC*BB][64] (hs of previous layer). grid (512,1), blk 256.
// md==0: MFMA, A split hi/lo bf16 in staging (fp32-grade precision).
// ---------------------------------------------------------------------------
__global__ __launch_bounds__(256) void projh_chunk(
    const float* __restrict__ A, const void* __restrict__ wih,
    const void* __restrict__ bih, const void* __restrict__ bhh,
    float* __restrict__ xp, const int* modep)
{
    const int md = *modep;
    __shared__ __align__(16) char smem[55296];   // mfma: 2*9216 + 36864
    const int tid = threadIdx.x;
    const int m0 = blockIdx.x * 64;
    if (md == 0) {
        unsigned short* Ahi = (unsigned short*)smem;   // [64][72]
        unsigned short* Alo = Ahi + 64 * 72;           // [64][72]
        unsigned short* Ws  = Alo + 64 * 72;           // [256][72]
        const int lane = tid & 63, wv = tid >> 6;
        const int fr = lane & 15, fq = lane >> 4;
        const int ar = tid >> 2, aq = (tid & 3) << 4;
        // stage A rows (fp32 -> hi/lo bf16)
        #pragma unroll
        for (int q = 0; q < 4; ++q) {
            float4 v = *(const float4*)(A + (long long)(m0 + ar) * HH + aq + q * 4);
            ushort4 hi, lo;
            hi.x = f2bf(v.x); lo.x = f2bf(v.x - bf2f(hi.x));
            hi.y = f2bf(v.y); lo.y = f2bf(v.y - bf2f(hi.y));
            hi.z = f2bf(v.z); lo.z = f2bf(v.z - bf2f(hi.z));
            hi.w = f2bf(v.w); lo.w = f2bf(v.w - bf2f(hi.w));
            *(ushort4*)(Ahi + ar * 72 + aq + q * 4) = hi;
            *(ushort4*)(Alo + ar * 72 + aq + q * 4) = lo;
        }
        // stage W: row tid (64 bf16 = 128B, 16B-aligned)
        {
            const uint4* gw = (const uint4*)((const unsigned short*)wih + (long long)tid * HH);
            #pragma unroll
            for (int q = 0; q < 8; ++q)
                *(uint4*)(Ws + tid * 72 + q * 8) = gw[q];
        }
        float bias[4];
        #pragma unroll
        for (int nf = 0; nf < 4; ++nf) {
            int n = wv * 64 + nf * 16 + fr;
            bias[nf] = ld1(bih, n, 0) + ld1(bhh, n, 0);
        }
        __syncthreads();
        bf16x8 bfr[4][2];
        #pragma unroll
        for (int nf = 0; nf < 4; ++nf) {
            #pragma unroll
            for (int kf = 0; kf < 2; ++kf)
                bfr[nf][kf] = *(const bf16x8*)(Ws + (wv * 64 + nf * 16 + fr) * 72 + kf * 32 + fq * 8);
        }
        f32x4 acc[4][4] = {};
        #pragma unroll
        for (int mf = 0; mf < 4; ++mf) {
            bf16x8 ah[2], al[2];
            #pragma unroll
            for (int kf = 0; kf < 2; ++kf) {
                ah[kf] = *(const bf16x8*)(Ahi + (mf * 16 + fr) * 72 + kf * 32 + fq * 8);
                al[kf] = *(const bf16x8*)(Alo + (mf * 16 + fr) * 72 + kf * 32 + fq * 8);
            }
            #pragma unroll
            for (int nf = 0; nf < 4; ++nf) {
                #pragma unroll
                for (int kf = 0; kf < 2; ++kf) {
                    acc[mf][nf] = mfma16(ah[kf], bfr[nf][kf], acc[mf][nf]);
                    acc[mf][nf] = mfma16(al[kf], bfr[nf][kf], acc[mf][nf]);
                }
            }
        }
        #pragma unroll
        for (int mf = 0; mf < 4; ++mf) {
            #pragma unroll
            for (int nf = 0; nf < 4; ++nf) {
                const int col = wv * 64 + nf * 16 + fr;
                #pragma unroll
                for (int r = 0; r < 4; ++r) {
                    const int row = m0 + mf * 16 + fq * 4 + r;
                    xp[(long long)row * XP + col] = acc[mf][nf][r] + bias[nf];
                }
            }
        }
    } else {
        float (*At)[68] = (float (*)[68])smem;
        float (*Wt)[68] = (float (*)[68])(smem + 64 * 68 * 4);
        const int lr = tid >> 2;
        const int lc = (tid & 3) * 16;
        const int tx = tid & 15, ty = tid >> 4;
        for (int ny = 0; ny < 4; ++ny) {
            const int n0 = ny * 64;
            #pragma unroll
            for (int q = 0; q < 4; ++q) {
                float4 av = *(const float4*)(A + (long long)(m0 + lr) * HH + lc + q * 4);
                float vw[4];
                ld4v(vw, wih, (long long)(n0 + lr) * HH + lc + q * 4, md);
                At[lc+q*4+0][lr]=av.x; At[lc+q*4+1][lr]=av.y; At[lc+q*4+2][lr]=av.z; At[lc+q*4+3][lr]=av.w;
                Wt[lc+q*4+0][lr]=vw[0]; Wt[lc+q*4+1][lr]=vw[1]; Wt[lc+q*4+2][lr]=vw[2]; Wt[lc+q*4+3][lr]=vw[3];
            }
            __syncthreads();
            float acc[4][4] = {{0.f,0.f,0.f,0.f},{0.f,0.f,0.f,0.f},{0.f,0.f,0.f,0.f},{0.f,0.f,0.f,0.f}};
            #pragma unroll 16
            for (int k = 0; k < 64; ++k) {
                float4 a = *(const float4*)&At[k][ty * 4];
                float4 bv = *(const float4*)&Wt[k][tx * 4];
                FMA4x4(a, bv)
            }
            float bias[4];
            #pragma unroll
            for (int j = 0; j < 4; ++j) {
                int n = n0 + tx * 4 + j;
                bias[j] = ld1(bih, n, md) + ld1(bhh, n, md);
            }
            #pragma unroll
            for (int i = 0; i < 4; ++i) {
                long long row = m0 + ty * 4 + i;
                float4 o = make_float4(acc[i][0] + bias[0], acc[i][1] + bias[1],
                                       acc[i][2] + bias[2], acc[i][3] + bias[3]);
                *(float4*)(xp + row * XP + n0 + tx * 4) = o;
            }
            __syncthreads();
        }
    }
}

// ---------------------------------------------------------------------------
// scan_chunk: recurrence over TC steps, 1 block per batch row, 256 threads.
// (unchanged this round)
// ---------------------------------------------------------------------------
__global__ __launch_bounds__(256) void scan_chunk(
    const float* __restrict__ xp, float* __restrict__ hs,
    const void* __restrict__ whh,
    float* __restrict__ hstate, float* __restrict__ cstate, const int* modep)
{
    const int md = *modep;
    const int b = blockIdx.x;
    const int j = threadIdx.x;
    const int g = ((j & 3) << 6) | (j >> 2);   // gate row this thread computes
    const int m = j & 63;                      // h-index this thread updates
    __shared__ __align__(16) float h_s[64];
    __shared__ __align__(16) float g_s[2][256];
    float w[64];
    #pragma unroll
    for (int q = 0; q < 16; ++q) {
        float v[4];
        ld4v(v, whh, (long long)g * HH + q * 4, md);
        w[4*q+0]=v[0]; w[4*q+1]=v[1]; w[4*q+2]=v[2]; w[4*q+3]=v[3];
    }
    float c = cstate[b * HH + m];
    h_s[m] = hstate[b * HH + m];   // every wave writes all 64 (same values)
    float hval = h_s[m];

    const int type = j & 3;
    const float aa = (type == 2) ? 2.f : 1.f;  // tanh(x) = 2*sig(2x)-1
    const float cc = 1.f - aa;

    const long long xbase = (long long)b * XP + g;
    const long long xstep = (long long)BB * XP;
    float xc[8], xn[8];
    #pragma unroll
    for (int p = 0; p < 8; ++p) xc[p] = xp[xbase + (long long)p * xstep];

    for (int tg = 0; tg < TC; tg += 8) {
        if (tg + 8 < TC) {
            #pragma unroll
            for (int p = 0; p < 8; ++p)
                xn[p] = xp[xbase + (long long)(tg + 8 + p) * xstep];
        }
        #pragma unroll
        for (int u = 0; u < 8; ++u) {
            const int t = tg + u;
            float a0 = xc[u], a1 = 0.f, a2 = 0.f, a3 = 0.f;
            const float4* h4 = (const float4*)h_s;
            #pragma unroll
            for (int q = 0; q < 16; ++q) {
                float4 hv = h4[q];
                a0 = fmaf(hv.x, w[4*q+0], a0);
                a1 = fmaf(hv.y, w[4*q+1], a1);
                a2 = fmaf(hv.z, w[4*q+2], a2);
                a3 = fmaf(hv.w, w[4*q+3], a3);
            }
            float gr = (a0 + a1) + (a2 + a3);
            float s = 1.f / (1.f + __expf(-aa * gr));
            g_s[t & 1][j] = fmaf(aa, s, cc);
            asm volatile("s_waitcnt lgkmcnt(0)\n\ts_barrier" ::: "memory");
            float4 gv = *(const float4*)&g_s[t & 1][4 * m];  // {i,f,g,o} for m
            c = gv.y * c + gv.x * gv.z;
            hval = gv.w * tanh_f(c);
            h_s[m] = hval;
            if (j < 64) hs[((long long)t * BB + b) * HH + m] = hval;
        }
        #pragma unroll
        for (int p = 0; p < 8; ++p) xc[p] = xn[p];
    }
    if (j < 64) {
        hstate[b * HH + m] = hval;
        cstate[b * HH + m] = c;
    }
}

// ---------------------------------------------------------------------------
// head_chunk: y = tanh(hs2 @ w1^T + b1) @ w2^T + b2 for one time chunk.
// md==0: MFMA; Z computed fp32, tanh'd, re-split hi/lo in LDS.
// ---------------------------------------------------------------------------
__global__ __launch_bounds__(256) void head_chunk(
    const float* __restrict__ hs, const void* __restrict__ w1,
    const void* __restrict__ b1, const void* __restrict__ w2,
    const void* __restrict__ b2, void* __restrict__ out,
    const int* modep, int chunk)
{
    const int md = *modep;
    __shared__ __align__(16) char smem[52224];  // max(fp32 3*17408, mfma 5*9216)
    const int tid = threadIdx.x;
    const int m0 = blockIdx.x * 64;
    const long long gbase = (long long)chunk * TC * BB;
    if (md == 0) {
        unsigned short* Ahi = (unsigned short*)smem;  // [64][72] each
        unsigned short* Alo = Ahi + 4608;
        unsigned short* Ws  = Alo + 4608;
        unsigned short* Zhi = Ws + 4608;
        unsigned short* Zlo = Zhi + 4608;
        const int lane = tid & 63, wv = tid >> 6;
        const int fr = lane & 15, fq = lane >> 4;
        const int ar = tid >> 2, aq = (tid & 3) << 4;
        // stage A = hs2 tile (hi/lo split)
        #pragma unroll
        for (int q = 0; q < 4; ++q) {
            float4 v = *(const float4*)(hs + (long long)(m0 + ar) * HH + aq + q * 4);
            ushort4 hi, lo;
            hi.x = f2bf(v.x); lo.x = f2bf(v.x - bf2f(hi.x));
            hi.y = f2bf(v.y); lo.y = f2bf(v.y - bf2f(hi.y));
            hi.z = f2bf(v.z); lo.z = f2bf(v.z - bf2f(hi.z));
            hi.w = f2bf(v.w); lo.w = f2bf(v.w - bf2f(hi.w));
            *(ushort4*)(Ahi + ar * 72 + aq + q * 4) = hi;
            *(ushort4*)(Alo + ar * 72 + aq + q * 4) = lo;
        }
        // stage w1 (row ar, 16 elems at aq)
        {
            const uint4* g1 = (const uint4*)((const unsigned short*)w1 + ar * HH + aq);
            *(uint4*)(Ws + ar * 72 + aq) = g1[0];
            *(uint4*)(Ws + ar * 72 + aq + 8) = g1[1];
        }
        __syncthreads();
        // phase 1: Z = tanh(A @ w1^T + b1); wave wv owns m-rows [wv*16, +16)
        {
            f32x4 acc[4] = {};
            bf16x8 ah[2], al[2];
            #pragma unroll
            for (int kf = 0; kf < 2; ++kf) {
                ah[kf] = *(const bf16x8*)(Ahi + (wv * 16 + fr) * 72 + kf * 32 + fq * 8);
                al[kf] = *(const bf16x8*)(Alo + (wv * 16 + fr) * 72 + kf * 32 + fq * 8);
            }
            #pragma unroll
            for (int nf = 0; nf < 4; ++nf) {
                #pragma unroll
                for (int kf = 0; kf < 2; ++kf) {
                    bf16x8 bfr = *(const bf16x8*)(Ws + (nf * 16 + fr) * 72 + kf * 32 + fq * 8);
                    acc[nf] = mfma16(ah[kf], bfr, acc[nf]);
                    acc[nf] = mfma16(al[kf], bfr, acc[nf]);
                }
            }
            #pragma unroll
            for (int nf = 0; nf < 4; ++nf) {
                float bb = ld1(b1, nf * 16 + fr, 0);
                #pragma unroll
                for (int r = 0; r < 4; ++r) {
                    float z = tanh_f(acc[nf][r] + bb);
                    unsigned short h = f2bf(z);
                    int zi = (wv * 16 + fq * 4 + r) * 72 + nf * 16 + fr;
                    Zhi[zi] = h;
                    Zlo[zi] = f2bf(z - bf2f(h));
                }
            }
        }
        __syncthreads();
        // phase 2: out = Z @ w2^T + b2, N=300 in 5 chunks of 64
        bf16x8 zh[2], zl[2];
        #pragma unroll
        for (int kf = 0; kf < 2; ++kf) {
            zh[kf] = *(const bf16x8*)(Zhi + (wv * 16 + fr) * 72 + kf * 32 + fq * 8);
            zl[kf] = *(const bf16x8*)(Zlo + (wv * 16 + fr) * 72 + kf * 32 + fq * 8);
        }
        for (int dt = 0; dt < 5; ++dt) {
            const int n = dt * 64 + ar;
            if (n < DD) {
                const uint4* g2 = (const uint4*)((const unsigned short*)w2 + (long long)n * HH + aq);
                *(uint4*)(Ws + ar * 72 + aq) = g2[0];
                *(uint4*)(Ws + ar * 72 + aq + 8) = g2[1];
            } else {
                uint4 zv = make_uint4(0, 0, 0, 0);
                *(uint4*)(Ws + ar * 72 + aq) = zv;
                *(uint4*)(Ws + ar * 72 + aq + 8) = zv;
            }
            __syncthreads();
            f32x4 acc[4] = {};
            #pragma unroll
            for (int nf = 0; nf < 4; ++nf) {
                #pragma unroll
                for (int kf = 0; kf < 2; ++kf) {
                    bf16x8 bfr = *(const bf16x8*)(Ws + (nf * 16 + fr) * 72 + kf * 32 + fq * 8);
                    acc[nf] = mfma16(zh[kf], bfr, acc[nf]);
                    acc[nf] = mfma16(zl[kf], bfr, acc[nf]);
                }
            }
            #pragma unroll
            for (int nf = 0; nf < 4; ++nf) {
                const int col = dt * 64 + nf * 16 + fr;
                if (col < DD) {
                    float bb = ld1(b2, col, 0);
                    #pragma unroll
                    for (int r = 0; r < 4; ++r) {
                        long long row = gbase + m0 + wv * 16 + fq * 4 + r;
                        ((unsigned short*)out)[row * DD + col] = f2bf(acc[nf][r] + bb);
                    }
                }
            }
            __syncthreads();
        }
    } else {
        float (*Ht)[68] = (float (*)[68])smem;
        float (*Wt)[68] = (float (*)[68])(smem + 17408);
        float (*Zt)[68] = (float (*)[68])(smem + 34816);
        const int lr = tid >> 2;
        const int lc = (tid & 3) * 16;
        const int tx = tid & 15, ty = tid >> 4;
        #pragma unroll
        for (int q = 0; q < 4; ++q) {
            float4 av = *(const float4*)(hs + (long long)(m0 + lr) * HH + lc + q * 4);
            float vw[4];
            ld4v(vw, w1, (long long)lr * HH + lc + q * 4, md);
            Ht[lc+q*4+0][lr]=av.x; Ht[lc+q*4+1][lr]=av.y; Ht[lc+q*4+2][lr]=av.z; Ht[lc+q*4+3][lr]=av.w;
            Wt[lc+q*4+0][lr]=vw[0]; Wt[lc+q*4+1][lr]=vw[1]; Wt[lc+q*4+2][lr]=vw[2]; Wt[lc+q*4+3][lr]=vw[3];
        }
        __syncthreads();
        {
            float acc[4][4] = {{0.f,0.f,0.f,0.f},{0.f,0.f,0.f,0.f},{0.f,0.f,0.f,0.f},{0.f,0.f,0.f,0.f}};
            #pragma unroll 16
            for (int k = 0; k < 64; ++k) {
                float4 a = *(const float4*)&Ht[k][ty * 4];
                float4 bv = *(const float4*)&Wt[k][tx * 4];
                FMA4x4(a, bv)
            }
            #pragma unroll
            for (int jj = 0; jj < 4; ++jj) {
                float bb = ld1(b1, tx * 4 + jj, md);
                #pragma unroll
                for (int ii = 0; ii < 4; ++ii)
                    Zt[tx * 4 + jj][ty * 4 + ii] = tanh_f(acc[ii][jj] + bb);
            }
        }
        __syncthreads();
        for (int dt = 0; dt < 5; ++dt) {
            const int d0 = dt * 64;
            if (d0 + lr < DD) {
                #pragma unroll
                for (int q = 0; q < 4; ++q) {
                    float vw[4];
                    ld4v(vw, w2, (long long)(d0 + lr) * HH + lc + q * 4, md);
                    Wt[lc+q*4+0][lr]=vw[0]; Wt[lc+q*4+1][lr]=vw[1];
                    Wt[lc+q*4+2][lr]=vw[2]; Wt[lc+q*4+3][lr]=vw[3];
                }
            }
            __syncthreads();
            float acc[4][4] = {{0.f,0.f,0.f,0.f},{0.f,0.f,0.f,0.f},{0.f,0.f,0.f,0.f},{0.f,0.f,0.f,0.f}};
            #pragma unroll 16
            for (int k = 0; k < 64; ++k) {
                float4 a = *(const float4*)&Zt[k][ty * 4];
                float4 bv = *(const float4*)&Wt[k][tx * 4];
                FMA4x4(a, bv)
            }
            const int d = d0 + tx * 4;
            if (d < DD) {
                float bb0 = ld1(b2, d + 0, md), bb1 = ld1(b2, d + 1, md);
                float bb2v = ld1(b2, d + 2, md), bb3 = ld1(b2, d + 3, md);
                #pragma unroll
                for (int ii = 0; ii < 4; ++ii) {
                    long long row = gbase + m0 + ty * 4 + ii;
                    float o0 = acc[ii][0] + bb0, o1 = acc[ii][1] + bb1;
                    float o2 = acc[ii][2] + bb2v, o3 = acc[ii][3] + bb3;
                    if (md) {
                        *(float4*)((float*)out + row * DD + d) = make_float4(o0, o1, o2, o3);
                    } else {
                        ushort4 o;
                        o.x = f2bf(o0); o.y = f2bf(o1); o.z = f2bf(o2); o.w = f2bf(o3);
                        *(ushort4*)((unsigned short*)out + row * DD + d) = o;
                    }
                }
            }
            __syncthreads();
        }
    }
}

// ---------------------------------------------------------------------------
extern "C" void kernel_launch(void* const* d_in, const int* in_sizes, int n_in,
                              void* d_out, int out_size, void* d_ws, size_t ws_size,
                              hipStream_t stream)
{
    const void* inp  = d_in[0];
    const void* h0   = d_in[1];
    const void* c0   = d_in[2];
    const void* wih0 = d_in[3];
    const void* whh0 = d_in[4];
    const void* bih0 = d_in[5];
    const void* bhh0 = d_in[6];
    const void* wih1 = d_in[7];
    const void* whh1 = d_in[8];
    const void* bih1 = d_in[9];
    const void* bhh1 = d_in[10];
    const void* wih2 = d_in[11];
    const void* whh2 = d_in[12];
    const void* bih2 = d_in[13];
    const void* bhh2 = d_in[14];
    const void* w1   = d_in[15];
    const void* b1   = d_in[16];
    const void* w2   = d_in[17];
    const void* b2   = d_in[18];

    int* mode = (int*)d_ws;
    float* wsf = (float*)d_ws;
    float* hstate = wsf + 16;                          // [3,256,64]
    float* cstate = hstate + 3 * BB * HH;
    float* xp  = cstate + 3 * BB * HH;                 // [TC*256, 256]
    float* hs0 = xp + (size_t)TC * BB * XP;            // [TC*256, 64]
    float* hs1 = hs0 + (size_t)TC * BB * HH;
    float* hs2 = hs1 + (size_t)TC * BB * HH;

    detect_kernel<<<1, 64, 0, stream>>>(inp, mode);
    init_state<<<192, 256, 0, stream>>>(h0, c0, hstate, cstate, mode);

    for (int c = 0; c < NC; ++c) {
        proj0_chunk<<<dim3(TC * BB / 64), 256, 0, stream>>>(
            inp, wih0, bih0, bhh0, xp, mode, c);
        scan_chunk<<<BB, 256, 0, stream>>>(
            xp, hs0, whh0, hstate, cstate, mode);
        projh_chunk<<<dim3(TC * BB / 64), 256, 0, stream>>>(
            hs0, wih1, bih1, bhh1, xp, mode);
        scan_chunk<<<BB, 256, 0, stream>>>(
            xp, hs1, whh1, hstate + BB * HH, cstate + BB * HH, mode);
        projh_chunk<<<dim3(TC * BB / 64), 256, 0, stream>>>(
            hs1, wih2, bih2, bhh2, xp, mode);
        scan_chunk<<<BB, 256, 0, stream>>>(
            xp, hs2, whh2, hstate + 2 * BB * HH, cstate + 2 * BB * HH, mode);
        head_chunk<<<TC * BB / 64, 256, 0, stream>>>(
            hs2, w1, b1, w2, b2, d_out, mode, c);
    }
    final_state<<<192, 256, 0, stream>>>(hstate, cstate, d_out, mode);
}

// Round 2
// 1649.154 us; speedup vs baseline: 1.2190x; 1.2190x over previous
//
#include <hip/hip_runtime.h>
#include <math.h>

// 3-layer LSTM (H=64, D=300, B=256, T=512) + MLP head (64 -> tanh 64 -> 300).
// R5: discovery — harness runs FP32 mode (md==1); R1's bf16 MFMA paths were dead.
//  - All GEMMs now use MFMA in BOTH modes via 3-way bf16 split (hi/mid/lo) of
//    each operand, 6-term products => error ~2^-24, fp32-faithful.
//  - Weights pre-split ONCE into workspace bf16 planes (split_w kernel).
//  - scan: intra-wave shfl gate exchange (4 adjacent lanes hold i,f,g,o of one
//    h-index) replaces the g_s LDS round-trip; h_s parity double-buffered,
//    still ONE barrier/step. Dot math bit-identical to previous rounds.

#define TT 512
#define BB 256
#define DD 300
#define HH 64
#define MM (TT * BB)
#define XP 256            // 4H
#define TC 128            // time chunk
#define NC (TT / TC)

typedef __attribute__((ext_vector_type(8))) short bf16x8;
typedef __attribute__((ext_vector_type(4))) float f32x4;

__device__ __forceinline__ float bf2f(unsigned short u) {
    return __uint_as_float(((unsigned int)u) << 16);
}
__device__ __forceinline__ unsigned short f2bf(float f) {
    unsigned int x = __float_as_uint(f);
    x += 0x7FFFu + ((x >> 16) & 1u);   // RNE
    return (unsigned short)(x >> 16);
}
__device__ __forceinline__ float tanh_f(float x) { return 1.f - 2.f / (__expf(2.f * x) + 1.f); }

// dual-mode loads: md==1 -> fp32 buffer, md==0 -> bf16 buffer
__device__ __forceinline__ float ld1(const void* p, long long i, int md) {
    return md ? ((const float*)p)[i] : bf2f(((const unsigned short*)p)[i]);
}
__device__ __forceinline__ void ld4v(float* d, const void* p, long long i, int md) {
    if (md) {
        float4 v = *(const float4*)((const float*)p + i);
        d[0] = v.x; d[1] = v.y; d[2] = v.z; d[3] = v.w;
    } else {
        ushort4 u = *(const ushort4*)((const unsigned short*)p + i);
        d[0] = bf2f(u.x); d[1] = bf2f(u.y); d[2] = bf2f(u.z); d[3] = bf2f(u.w);
    }
}

__device__ __forceinline__ f32x4 mfma16(bf16x8 a, bf16x8 b, f32x4 c) {
    return __builtin_amdgcn_mfma_f32_16x16x32_bf16(a, b, c, 0, 0, 0);
}

// 6-term split product: (a1+a2+a3)*(b1+b2+b3), dropping terms < 2^-24
__device__ __forceinline__ f32x4 mfma6(bf16x8 a1, bf16x8 a2, bf16x8 a3,
                                       bf16x8 b1, bf16x8 b2, bf16x8 b3, f32x4 t) {
    t = mfma16(a2, b2, t);
    t = mfma16(a1, b3, t);
    t = mfma16(a3, b1, t);
    t = mfma16(a1, b2, t);
    t = mfma16(a2, b1, t);
    t = mfma16(a1, b1, t);
    return t;
}

// 3-way bf16 split of 4 floats
__device__ __forceinline__ void split3x4(const float* v, ushort4& h1, ushort4& h2, ushort4& h3) {
    unsigned short a[4], b[4], c[4];
    #pragma unroll
    for (int e = 0; e < 4; ++e) {
        unsigned short x = f2bf(v[e]);
        float r1 = v[e] - bf2f(x);
        unsigned short y = f2bf(r1);
        float r2 = r1 - bf2f(y);
        unsigned short z = f2bf(r2);
        a[e] = x; b[e] = y; c[e] = z;
    }
    h1 = make_ushort4(a[0], a[1], a[2], a[3]);
    h2 = make_ushort4(b[0], b[1], b[2], b[3]);
    h3 = make_ushort4(c[0], c[1], c[2], c[3]);
}

// ---------------------------------------------------------------------------
__global__ void detect_kernel(const void* inp, int* mode) {
    if (threadIdx.x == 0 && blockIdx.x == 0) {
        const unsigned short* u = (const unsigned short*)inp;
        int bad = 0;
        for (int i = 0; i < 256; ++i) {
            float f = bf2f(u[i]);
            if (!(f == f) || fabsf(f) > 1e6f) ++bad;
        }
        *mode = (bad >= 4) ? 1 : 0;
    }
}

__global__ __launch_bounds__(256) void init_state(
    const void* h0, const void* c0, float* hstate, float* cstate, const int* modep)
{
    const int md = *modep;
    int i = blockIdx.x * 256 + threadIdx.x;
    if (i < 3 * BB * HH) {
        hstate[i] = ld1(h0, i, md);
        cstate[i] = ld1(c0, i, md);
    }
}

__global__ __launch_bounds__(256) void final_state(
    const float* hstate, const float* cstate, void* out, const int* modep)
{
    const int md = *modep;
    int i = blockIdx.x * 256 + threadIdx.x;
    const long long base = (long long)MM * DD;
    if (i < 3 * BB * HH) {
        if (md) {
            ((float*)out)[base + i] = hstate[i];
            ((float*)out)[base + 3 * BB * HH + i] = cstate[i];
        } else {
            ((unsigned short*)out)[base + i] = f2bf(hstate[i]);
            ((unsigned short*)out)[base + 3 * BB * HH + i] = f2bf(cstate[i]);
        }
    }
}

// ---------------------------------------------------------------------------
// split_w: pre-split a weight tensor into 3 bf16 planes [rdst][cdst] (padded
// with zeros beyond rsrc/csrc). dst layout: [hi | mid | lo], each rdst*cdst.
// ---------------------------------------------------------------------------
__global__ __launch_bounds__(256) void split_w(
    const void* __restrict__ src, unsigned short* __restrict__ dst,
    int rsrc, int csrc, int rdst, int cdst, const int* modep)
{
    const int md = *modep;
    int i = blockIdx.x * 256 + threadIdx.x;
    int n = rdst * cdst;
    if (i >= n) return;
    int r = i / cdst, cc = i - r * cdst;
    float v = (r < rsrc && cc < csrc) ? ld1(src, (long long)r * csrc + cc, md) : 0.f;
    unsigned short a = f2bf(v);
    float r1 = v - bf2f(a);
    unsigned short b = f2bf(r1);
    float r2 = r1 - bf2f(b);
    unsigned short c = f2bf(r2);
    dst[i] = a; dst[n + i] = b; dst[2 * n + i] = c;
}

// ---------------------------------------------------------------------------
// proj0_chunk: xp[ml][n] = sum_k input(b,t,k)*wih0[n][k] + bih0[n]+bhh0[n]
// grid 512, blk 256. MFMA split-product. W pre-split planes [256][320].
// K panels of 32 (10 panels). LDS ~76.8KB -> 2 blocks/CU.
// ---------------------------------------------------------------------------
__global__ __launch_bounds__(256, 2) void proj0_chunk(
    const void* __restrict__ inp, const unsigned short* __restrict__ wsp,
    const void* __restrict__ bih, const void* __restrict__ bhh,
    float* __restrict__ xp, const int* modep, int chunk)
{
    const int md = *modep;
    __shared__ __align__(16) unsigned short aS[3][64 * 40];
    __shared__ __align__(16) unsigned short wS[3][256 * 40];
    const int tid = threadIdx.x;
    const int m0 = blockIdx.x * 64;
    const int lane = tid & 63, wv = tid >> 6;
    const int fr = lane & 15, fq = lane >> 4;
    const int ar = tid >> 2, acs = (tid & 3) * 8;
    const int ml = m0 + ar;
    const int b = ml & 255;
    const int t = chunk * TC + (ml >> 8);
    const long long abase = (long long)b * (TT * DD) + (long long)t * DD;
    float bias[4];
    #pragma unroll
    for (int nf = 0; nf < 4; ++nf) {
        int n = wv * 64 + nf * 16 + fr;
        bias[nf] = ld1(bih, n, md) + ld1(bhh, n, md);
    }
    f32x4 acc[4][4] = {};
    for (int p = 0; p < 10; ++p) {
        const int k0 = p * 32;
        // stage A (row ar, 8 cols at acs), 3-way split
        #pragma unroll
        for (int q = 0; q < 2; ++q) {
            const int kg = k0 + acs + q * 4;
            float v[4];
            if (kg + 3 < DD) {
                ld4v(v, inp, abase + kg, md);
            } else {
                #pragma unroll
                for (int e = 0; e < 4; ++e)
                    v[e] = (kg + e < DD) ? ld1(inp, abase + kg + e, md) : 0.f;
            }
            ushort4 h1, h2, h3;
            split3x4(v, h1, h2, h3);
            *(ushort4*)(&aS[0][ar * 40 + acs + q * 4]) = h1;
            *(ushort4*)(&aS[1][ar * 40 + acs + q * 4]) = h2;
            *(ushort4*)(&aS[2][ar * 40 + acs + q * 4]) = h3;
        }
        // stage W: row tid, 32 cols, 3 pre-split planes (pure copies)
        #pragma unroll
        for (int pl = 0; pl < 3; ++pl) {
            const uint4* gw = (const uint4*)(wsp + (size_t)pl * 81920 + (size_t)tid * 320 + k0);
            uint4* dw = (uint4*)(&wS[pl][tid * 40]);
            #pragma unroll
            for (int qq = 0; qq < 4; ++qq) dw[qq] = gw[qq];
        }
        __syncthreads();
        bf16x8 wf[4][3];
        #pragma unroll
        for (int nf = 0; nf < 4; ++nf) {
            #pragma unroll
            for (int pl = 0; pl < 3; ++pl)
                wf[nf][pl] = *(const bf16x8*)(&wS[pl][(wv * 64 + nf * 16 + fr) * 40 + fq * 8]);
        }
        #pragma unroll
        for (int mf = 0; mf < 4; ++mf) {
            bf16x8 a1 = *(const bf16x8*)(&aS[0][(mf * 16 + fr) * 40 + fq * 8]);
            bf16x8 a2 = *(const bf16x8*)(&aS[1][(mf * 16 + fr) * 40 + fq * 8]);
            bf16x8 a3 = *(const bf16x8*)(&aS[2][(mf * 16 + fr) * 40 + fq * 8]);
            #pragma unroll
            for (int nf = 0; nf < 4; ++nf)
                acc[mf][nf] = mfma6(a1, a2, a3, wf[nf][0], wf[nf][1], wf[nf][2], acc[mf][nf]);
        }
        __syncthreads();
    }
    // C/D layout: col = lane&15, row = (lane>>4)*4 + reg
    #pragma unroll
    for (int mf = 0; mf < 4; ++mf) {
        #pragma unroll
        for (int nf = 0; nf < 4; ++nf) {
            const int col = wv * 64 + nf * 16 + fr;
            #pragma unroll
            for (int r = 0; r < 4; ++r) {
                const int row = m0 + mf * 16 + fq * 4 + r;
                xp[(long long)row * XP + col] = acc[mf][nf][r] + bias[nf];
            }
        }
    }
}

// ---------------------------------------------------------------------------
// projh_chunk: xp[m][n] = sum_k A[m][k]*wih[n][k] + bih[n]+bhh[n]
// A fp32 [TC*BB][64]. W pre-split planes [256][64]. K panels of 32 (2 panels).
// ---------------------------------------------------------------------------
__global__ __launch_bounds__(256, 2) void projh_chunk(
    const float* __restrict__ A, const unsigned short* __restrict__ wsp,
    const void* __restrict__ bih, const void* __restrict__ bhh,
    float* __restrict__ xp, const int* modep)
{
    const int md = *modep;
    __shared__ __align__(16) unsigned short aS[3][64 * 40];
    __shared__ __align__(16) unsigned short wS[3][256 * 40];
    const int tid = threadIdx.x;
    const int m0 = blockIdx.x * 64;
    const int lane = tid & 63, wv = tid >> 6;
    const int fr = lane & 15, fq = lane >> 4;
    const int ar = tid >> 2, acs = (tid & 3) * 8;
    float bias[4];
    #pragma unroll
    for (int nf = 0; nf < 4; ++nf) {
        int n = wv * 64 + nf * 16 + fr;
        bias[nf] = ld1(bih, n, md) + ld1(bhh, n, md);
    }
    f32x4 acc[4][4] = {};
    #pragma unroll
    for (int p = 0; p < 2; ++p) {
        const int k0 = p * 32;
        #pragma unroll
        for (int q = 0; q < 2; ++q) {
            float v[4];
            const float4 fv = *(const float4*)(A + (long long)(m0 + ar) * HH + k0 + acs + q * 4);
            v[0] = fv.x; v[1] = fv.y; v[2] = fv.z; v[3] = fv.w;
            ushort4 h1, h2, h3;
            split3x4(v, h1, h2, h3);
            *(ushort4*)(&aS[0][ar * 40 + acs + q * 4]) = h1;
            *(ushort4*)(&aS[1][ar * 40 + acs + q * 4]) = h2;
            *(ushort4*)(&aS[2][ar * 40 + acs + q * 4]) = h3;
        }
        #pragma unroll
        for (int pl = 0; pl < 3; ++pl) {
            const uint4* gw = (const uint4*)(wsp + (size_t)pl * 16384 + (size_t)tid * 64 + k0);
            uint4* dw = (uint4*)(&wS[pl][tid * 40]);
            #pragma unroll
            for (int qq = 0; qq < 4; ++qq) dw[qq] = gw[qq];
        }
        __syncthreads();
        bf16x8 wf[4][3];
        #pragma unroll
        for (int nf = 0; nf < 4; ++nf) {
            #pragma unroll
            for (int pl = 0; pl < 3; ++pl)
                wf[nf][pl] = *(const bf16x8*)(&wS[pl][(wv * 64 + nf * 16 + fr) * 40 + fq * 8]);
        }
        #pragma unroll
        for (int mf = 0; mf < 4; ++mf) {
            bf16x8 a1 = *(const bf16x8*)(&aS[0][(mf * 16 + fr) * 40 + fq * 8]);
            bf16x8 a2 = *(const bf16x8*)(&aS[1][(mf * 16 + fr) * 40 + fq * 8]);
            bf16x8 a3 = *(const bf16x8*)(&aS[2][(mf * 16 + fr) * 40 + fq * 8]);
            #pragma unroll
            for (int nf = 0; nf < 4; ++nf)
                acc[mf][nf] = mfma6(a1, a2, a3, wf[nf][0], wf[nf][1], wf[nf][2], acc[mf][nf]);
        }
        __syncthreads();
    }
    #pragma unroll
    for (int mf = 0; mf < 4; ++mf) {
        #pragma unroll
        for (int nf = 0; nf < 4; ++nf) {
            const int col = wv * 64 + nf * 16 + fr;
            #pragma unroll
            for (int r = 0; r < 4; ++r) {
                const int row = m0 + mf * 16 + fq * 4 + r;
                xp[(long long)row * XP + col] = acc[mf][nf][r] + bias[nf];
            }
        }
    }
}

// ---------------------------------------------------------------------------
// scan_chunk: recurrence over TC steps, 1 block per batch row, 256 threads.
// Thread j: gate type tau=j&3 of h-index i=j>>2 (gate row g = tau*64+i).
// The 4 gate values of index i live in 4 ADJACENT LANES of one wave -> shfl
// exchange (no LDS round-trip for gates). h_s parity double-buffered so one
// barrier/step suffices (write buf[t^1] while others may still read buf[t]).
// Dot-product code identical to previous rounds (bit-identical numerics).
// ---------------------------------------------------------------------------
__global__ __launch_bounds__(256) void scan_chunk(
    const float* __restrict__ xp, float* __restrict__ hs,
    const void* __restrict__ whh,
    float* __restrict__ hstate, float* __restrict__ cstate, const int* modep)
{
    const int md = *modep;
    const int b = blockIdx.x;
    const int j = threadIdx.x;
    const int g = ((j & 3) << 6) | (j >> 2);   // gate row this thread computes
    const int i = j >> 2;                      // h-index of this lane group
    const int m = j & 63;                      // init helper
    const int bl = j & 60;                     // lane-group base within wave
    __shared__ __align__(16) float h_s[2][64];
    float w[64];
    #pragma unroll
    for (int q = 0; q < 16; ++q) {
        float v[4];
        ld4v(v, whh, (long long)g * HH + q * 4, md);
        w[4*q+0]=v[0]; w[4*q+1]=v[1]; w[4*q+2]=v[2]; w[4*q+3]=v[3];
    }
    float c = cstate[b * HH + i];
    h_s[0][m] = hstate[b * HH + m];   // every wave writes all 64 (same values)
    float hval = 0.f;

    const int type = j & 3;
    const float aa = (type == 2) ? 2.f : 1.f;  // tanh(x) = 2*sig(2x)-1
    const float cc = 1.f - aa;

    const long long xbase = (long long)b * XP + g;
    const long long xstep = (long long)BB * XP;
    float xc[8], xn[8];
    #pragma unroll
    for (int p = 0; p < 8; ++p) xc[p] = xp[xbase + (long long)p * xstep];

    for (int tg = 0; tg < TC; tg += 8) {
        if (tg + 8 < TC) {
            #pragma unroll
            for (int p = 0; p < 8; ++p)
                xn[p] = xp[xbase + (long long)(tg + 8 + p) * xstep];
        }
        #pragma unroll
        for (int u = 0; u < 8; ++u) {
            const int t = tg + u;
            float a0 = xc[u], a1 = 0.f, a2 = 0.f, a3 = 0.f;
            const float4* h4 = (const float4*)h_s[t & 1];
            #pragma unroll
            for (int q = 0; q < 16; ++q) {
                float4 hv = h4[q];
                a0 = fmaf(hv.x, w[4*q+0], a0);
                a1 = fmaf(hv.y, w[4*q+1], a1);
                a2 = fmaf(hv.z, w[4*q+2], a2);
                a3 = fmaf(hv.w, w[4*q+3], a3);
            }
            float gr = (a0 + a1) + (a2 + a3);
            float s = 1.f / (1.f + __expf(-aa * gr));
            float y = fmaf(aa, s, cc);
            // gate exchange within the 4-lane group (i,f,g,o)
            float yi = __shfl(y, bl | 0);
            float yf = __shfl(y, bl | 1);
            float yg = __shfl(y, bl | 2);
            float yo = __shfl(y, bl | 3);
            c = yf * c + yi * yg;
            hval = yo * tanh_f(c);
            if ((j & 3) == 0) {
                h_s[(t & 1) ^ 1][i] = hval;
                hs[((long long)t * BB + b) * HH + i] = hval;
            }
            asm volatile("s_waitcnt lgkmcnt(0)\n\ts_barrier" ::: "memory");
        }
        #pragma unroll
        for (int p = 0; p < 8; ++p) xc[p] = xn[p];
    }
    if ((j & 3) == 0) {
        hstate[b * HH + i] = hval;
        cstate[b * HH + i] = c;
    }
}

// ---------------------------------------------------------------------------
// head_chunk: y = tanh(hs2 @ w1^T + b1) @ w2^T + b2, MFMA split-product.
// w1 planes [64][64], w2 planes [320][64] (rows>=300 zero). LDS ~83KB.
// ---------------------------------------------------------------------------
__global__ __launch_bounds__(256, 1) void head_chunk(
    const float* __restrict__ hs, const unsigned short* __restrict__ w1p,
    const void* __restrict__ b1, const unsigned short* __restrict__ w2p,
    const void* __restrict__ b2, void* __restrict__ out,
    const int* modep, int chunk)
{
    const int md = *modep;
    __shared__ __align__(16) unsigned short aS[3][64 * 72];
    __shared__ __align__(16) unsigned short wS[3][64 * 72];
    __shared__ __align__(16) unsigned short zS[3][64 * 72];
    const int tid = threadIdx.x;
    const int m0 = blockIdx.x * 64;
    const long long gbase = (long long)chunk * TC * BB;
    const int lane = tid & 63, wv = tid >> 6;
    const int fr = lane & 15, fq = lane >> 4;
    const int ar = tid >> 2, cs = (tid & 3) * 16;
    // stage A = hs tile (3-way split) and w1 planes (copy)
    #pragma unroll
    for (int e = 0; e < 4; ++e) {
        float v[4];
        const float4 fv = *(const float4*)(hs + (long long)(m0 + ar) * HH + cs + e * 4);
        v[0] = fv.x; v[1] = fv.y; v[2] = fv.z; v[3] = fv.w;
        ushort4 h1, h2, h3;
        split3x4(v, h1, h2, h3);
        *(ushort4*)(&aS[0][ar * 72 + cs + e * 4]) = h1;
        *(ushort4*)(&aS[1][ar * 72 + cs + e * 4]) = h2;
        *(ushort4*)(&aS[2][ar * 72 + cs + e * 4]) = h3;
    }
    #pragma unroll
    for (int pl = 0; pl < 3; ++pl) {
        const uint4* g1 = (const uint4*)(w1p + (size_t)pl * 4096 + (size_t)ar * 64 + cs);
        *(uint4*)(&wS[pl][ar * 72 + cs]) = g1[0];
        *(uint4*)(&wS[pl][ar * 72 + cs + 8]) = g1[1];
    }
    __syncthreads();
    // phase 1: Z = tanh(A @ w1^T + b1); wave wv owns m-rows [wv*16, +16)
    {
        bf16x8 af[2][3];
        #pragma unroll
        for (int kf = 0; kf < 2; ++kf) {
            #pragma unroll
            for (int pl = 0; pl < 3; ++pl)
                af[kf][pl] = *(const bf16x8*)(&aS[pl][(wv * 16 + fr) * 72 + kf * 32 + fq * 8]);
        }
        f32x4 acc1[4] = {};
        #pragma unroll
        for (int nf = 0; nf < 4; ++nf) {
            #pragma unroll
            for (int kf = 0; kf < 2; ++kf) {
                bf16x8 b1f = *(const bf16x8*)(&wS[0][(nf * 16 + fr) * 72 + kf * 32 + fq * 8]);
                bf16x8 b2f = *(const bf16x8*)(&wS[1][(nf * 16 + fr) * 72 + kf * 32 + fq * 8]);
                bf16x8 b3f = *(const bf16x8*)(&wS[2][(nf * 16 + fr) * 72 + kf * 32 + fq * 8]);
                acc1[nf] = mfma6(af[kf][0], af[kf][1], af[kf][2], b1f, b2f, b3f, acc1[nf]);
            }
        }
        #pragma unroll
        for (int nf = 0; nf < 4; ++nf) {
            float bb = ld1(b1, nf * 16 + fr, md);
            #pragma unroll
            for (int r = 0; r < 4; ++r) {
                float z = tanh_f(acc1[nf][r] + bb);
                unsigned short zh = f2bf(z);
                float r1 = z - bf2f(zh);
                unsigned short zm = f2bf(r1);
                float r2 = r1 - bf2f(zm);
                unsigned short zl = f2bf(r2);
                int zi = (wv * 16 + fq * 4 + r) * 72 + nf * 16 + fr;
                zS[0][zi] = zh; zS[1][zi] = zm; zS[2][zi] = zl;
            }
        }
    }
    __syncthreads();
    // hoist Z fragments (stable across dt loop)
    bf16x8 zf[2][3];
    #pragma unroll
    for (int kf = 0; kf < 2; ++kf) {
        #pragma unroll
        for (int pl = 0; pl < 3; ++pl)
            zf[kf][pl] = *(const bf16x8*)(&zS[pl][(wv * 16 + fr) * 72 + kf * 32 + fq * 8]);
    }
    // phase 2: out = Z @ w2^T + b2, N=300 in 5 chunks of 64
    for (int dt = 0; dt < 5; ++dt) {
        #pragma unroll
        for (int pl = 0; pl < 3; ++pl) {
            const uint4* g2 = (const uint4*)(w2p + (size_t)pl * 20480 + (size_t)(dt * 64 + ar) * 64 + cs);
            *(uint4*)(&wS[pl][ar * 72 + cs]) = g2[0];
            *(uint4*)(&wS[pl][ar * 72 + cs + 8]) = g2[1];
        }
        __syncthreads();
        f32x4 acc[4] = {};
        #pragma unroll
        for (int nf = 0; nf < 4; ++nf) {
            #pragma unroll
            for (int kf = 0; kf < 2; ++kf) {
                bf16x8 b1f = *(const bf16x8*)(&wS[0][(nf * 16 + fr) * 72 + kf * 32 + fq * 8]);
                bf16x8 b2f = *(const bf16x8*)(&wS[1][(nf * 16 + fr) * 72 + kf * 32 + fq * 8]);
                bf16x8 b3f = *(const bf16x8*)(&wS[2][(nf * 16 + fr) * 72 + kf * 32 + fq * 8]);
                acc[nf] = mfma6(zf[kf][0], zf[kf][1], zf[kf][2], b1f, b2f, b3f, acc[nf]);
            }
        }
        #pragma unroll
        for (int nf = 0; nf < 4; ++nf) {
            const int col = dt * 64 + nf * 16 + fr;
            if (col < DD) {
                float bb = ld1(b2, col, md);
                #pragma unroll
                for (int r = 0; r < 4; ++r) {
                    long long row = gbase + m0 + wv * 16 + fq * 4 + r;
                    float o = acc[nf][r] + bb;
                    if (md) ((float*)out)[row * DD + col] = o;
                    else    ((unsigned short*)out)[row * DD + col] = f2bf(o);
                }
            }
        }
        __syncthreads();
    }
}

// ---------------------------------------------------------------------------
extern "C" void kernel_launch(void* const* d_in, const int* in_sizes, int n_in,
                              void* d_out, int out_size, void* d_ws, size_t ws_size,
                              hipStream_t stream)
{
    const void* inp  = d_in[0];
    const void* h0   = d_in[1];
    const void* c0   = d_in[2];
    const void* wih0 = d_in[3];
    const void* whh0 = d_in[4];
    const void* bih0 = d_in[5];
    const void* bhh0 = d_in[6];
    const void* wih1 = d_in[7];
    const void* whh1 = d_in[8];
    const void* bih1 = d_in[9];
    const void* bhh1 = d_in[10];
    const void* wih2 = d_in[11];
    const void* whh2 = d_in[12];
    const void* bih2 = d_in[13];
    const void* bhh2 = d_in[14];
    const void* w1   = d_in[15];
    const void* b1   = d_in[16];
    const void* w2   = d_in[17];
    const void* b2   = d_in[18];

    int* mode = (int*)d_ws;
    float* wsf = (float*)d_ws;
    float* hstate = wsf + 16;                          // [3,256,64]
    float* cstate = hstate + 3 * BB * HH;
    float* xp  = cstate + 3 * BB * HH;                 // [TC*256, 256]
    float* hs  = xp + (size_t)TC * BB * XP;            // [TC*256, 64] (reused per layer)
    unsigned short* w0s = (unsigned short*)(hs + (size_t)TC * BB * HH);
    unsigned short* w1s = w0s + (size_t)3 * 81920;     // [3][256*320]
    unsigned short* w2s = w1s + (size_t)3 * 16384;     // [3][256*64]
    unsigned short* h1s = w2s + (size_t)3 * 16384;     // [3][256*64]
    unsigned short* h2s = h1s + (size_t)3 * 4096;      // [3][64*64]
                                                       // h2s: [3][320*64]

    detect_kernel<<<1, 64, 0, stream>>>(inp, mode);
    init_state<<<192, 256, 0, stream>>>(h0, c0, hstate, cstate, mode);
    split_w<<<320, 256, 0, stream>>>(wih0, w0s, 256, 300, 256, 320, mode);
    split_w<<<64, 256, 0, stream>>>(wih1, w1s, 256, 64, 256, 64, mode);
    split_w<<<64, 256, 0, stream>>>(wih2, w2s, 256, 64, 256, 64, mode);
    split_w<<<16, 256, 0, stream>>>(w1, h1s, 64, 64, 64, 64, mode);
    split_w<<<80, 256, 0, stream>>>(w2, h2s, 300, 64, 320, 64, mode);

    for (int c = 0; c < NC; ++c) {
        proj0_chunk<<<dim3(TC * BB / 64), 256, 0, stream>>>(
            inp, w0s, bih0, bhh0, xp, mode, c);
        scan_chunk<<<BB, 256, 0, stream>>>(
            xp, hs, whh0, hstate, cstate, mode);
        projh_chunk<<<dim3(TC * BB / 64), 256, 0, stream>>>(
            hs, w1s, bih1, bhh1, xp, mode);
        scan_chunk<<<BB, 256, 0, stream>>>(
            xp, hs, whh1, hstate + BB * HH, cstate + BB * HH, mode);
        projh_chunk<<<dim3(TC * BB / 64), 256, 0, stream>>>(
            hs, w2s, bih2, bhh2, xp, mode);
        scan_chunk<<<BB, 256, 0, stream>>>(
            xp, hs, whh2, hstate + 2 * BB * HH, cstate + 2 * BB * HH, mode);
        head_chunk<<<TC * BB / 64, 256, 0, stream>>>(
            hs, h1s, b1, h2s, b2, d_out, mode, c);
    }
    final_state<<<192, 256, 0, stream>>>(hstate, cstate, d_out, mode);
}